// Round 16
// baseline (215.506 us; speedup 1.0000x reference)
//
#include <hip/hip_runtime.h>

// ---------------------------------------------------------------------------
// TTLinear on MI355X — round 15: R14 proven config + XCD-aware k_q decode.
// 8-phase arc closed (7 attempts, none beat m97's 85.8us; R15 confirmed the
// compiler caps 512-thread kernels at 128 VGPR -> fragments can't be hoisted).
//   k_cvt : X, t_q, W1, W2 -> bf16 (memory floor ~32us)
//   k_q   : Q = X @ t_q^T   m97 128x128, unswapped coalesced epilogue,
//           NEW: 1D grid, m0=(wg>>3)*128 n0=(wg&7)*128 — consecutive 8 wgs
//           (round-robin over 8 XCDs) share one A-panel (L3 temporal reuse),
//           each XCD keeps its fixed 256KB B-panel L2-resident.
//   k_l1  : h2 = gelu(Q@W1^T+b1)   (swapped vector epilogue)
//   k_l2  : out = Q + h2@W2^T + b2 (swapped vector epilogue)
// ---------------------------------------------------------------------------

#define DD      1024
#define HH      1024
#define H4      256
#define MROWS   32768          // T*N = 128*256

typedef unsigned short u16;
typedef __bf16 bf16x8 __attribute__((ext_vector_type(8)));
typedef float  f32x4  __attribute__((ext_vector_type(4)));

__device__ __forceinline__ u16 f2b(float x) {            // fp32 -> bf16 (RNE)
  unsigned u = __builtin_bit_cast(unsigned, x);
  unsigned r = (u + 0x7fffu + ((u >> 16) & 1u)) >> 16;
  return (u16)r;
}
__device__ __forceinline__ float b2f(u16 x) {
  return __builtin_bit_cast(float, ((unsigned)x) << 16);
}

__device__ __forceinline__ void gload16(const u16* g, u16* l) {
  __builtin_amdgcn_global_load_lds(
      (const __attribute__((address_space(1))) unsigned int*)g,
      (__attribute__((address_space(3))) unsigned int*)l, 16, 0, 0);
}

// ---------------------------------------------------------------------------
// fp32 -> bf16 bulk convert, 8 elems/thread; all four tensors in one launch.
// ---------------------------------------------------------------------------
__device__ __forceinline__ void cvt8_at(u16* dst, const float* src, size_t i) {
  const float4* s = (const float4*)(src + i);
  const float4 f0 = s[0], f1 = s[1];
  uint4 pk;
  pk.x = (unsigned)f2b(f0.x) | ((unsigned)f2b(f0.y) << 16);
  pk.y = (unsigned)f2b(f0.z) | ((unsigned)f2b(f0.w) << 16);
  pk.z = (unsigned)f2b(f1.x) | ((unsigned)f2b(f1.y) << 16);
  pk.w = (unsigned)f2b(f1.z) | ((unsigned)f2b(f1.w) << 16);
  *(uint4*)(dst + i) = pk;
}

__global__ __launch_bounds__(256) void k_cvt(
    const float* __restrict__ X, const float* __restrict__ tq,
    const float* __restrict__ W1, const float* __restrict__ W2,
    u16* __restrict__ Xb, u16* __restrict__ tqb,
    u16* __restrict__ W1b, u16* __restrict__ W2b) {
  const int b = blockIdx.x;
  if (b < 16384)      cvt8_at(Xb,  X,  ((size_t)b * 256 + threadIdx.x) * 8);
  else if (b < 16896) cvt8_at(tqb, tq, ((size_t)(b - 16384) * 256 + threadIdx.x) * 8);
  else if (b < 17024) cvt8_at(W1b, W1, ((size_t)(b - 16896) * 256 + threadIdx.x) * 8);
  else                cvt8_at(W2b, W2, ((size_t)(b - 17024) * 256 + threadIdx.x) * 8);
}

// ---------------------------------------------------------------------------
// m97 128x128 bf16 MFMA GEMM.  C(m,n) = sum_k A[m][k] * B[n][k]
// SWAP=0: mfma(aF,bF) -> reg axis = m, lane axis = n (coalesced scalar st).
// SWAP=1: mfma(bF,aF) -> reg axis = n (per-lane ushort4/float4 epilogue).
// XCDSWZ: 1D grid, m0=(wg>>3)*128, n0=(wg&7)*128 (A-panel shared by 8
//         consecutive wgs on 8 XCDs; B-panel pinned per XCD).
// MODE 0: bf16 store.  MODE 1: gelu -> bf16.  MODE 2: fp32 residual + bias.
// ---------------------------------------------------------------------------
template<int MODE, int SWAP, int XCDSWZ, int LDA, int LDB, int K, int LDC>
__global__ __launch_bounds__(256) void k_gemm(
    const u16* __restrict__ A, const u16* __restrict__ B,
    const float* __restrict__ bias, const u16* __restrict__ Qb,
    u16* __restrict__ outb, float* __restrict__ outf)
{
  __shared__ u16 smA[128 * 64];
  __shared__ u16 smB[128 * 64];
  const int tid  = threadIdx.x;
  int m0, n0;
  if (XCDSWZ) {
    const int wg = blockIdx.x;
    m0 = (wg >> 3) * 128;
    n0 = (wg & 7) * 128;
  } else {
    m0 = blockIdx.x * 128;
    n0 = blockIdx.y * 128;
  }
  const int lane = tid & 63, w = tid >> 6;
  const int wr = w >> 1, wc = w & 1;
  const int lr = lane & 15, lg = lane >> 4;

  const int r0 = w * 8 + (lane >> 3);
  const int cb = (lane & 7) ^ (r0 & 7);
  const u16* ga = A + (size_t)(m0 + r0) * LDA + cb * 8;
  const u16* gb = B + (size_t)(n0 + r0) * LDB + cb * 8;
  u16* lA = smA + w * 512;
  u16* lB = smB + w * 512;

  f32x4 acc[4][4];
  #pragma unroll
  for (int i = 0; i < 4; ++i)
    #pragma unroll
    for (int j = 0; j < 4; ++j) { f32x4 z = {0.f, 0.f, 0.f, 0.f}; acc[i][j] = z; }

  for (int k0 = 0; k0 < K; k0 += 64) {
    #pragma unroll
    for (int j = 0; j < 4; ++j) {
      gload16(ga + (size_t)j * 32 * LDA + k0, lA + j * 2048);
      gload16(gb + (size_t)j * 32 * LDB + k0, lB + j * 2048);
    }
    __syncthreads();
    #pragma unroll
    for (int kc = 0; kc < 2; ++kc) {
      const int blk = kc * 4 + lg;
      bf16x8 aF[4], bF[4];
      #pragma unroll
      for (int mi = 0; mi < 4; ++mi) {
        const int row = wr * 64 + mi * 16 + lr;
        aF[mi] = *(const bf16x8*)&smA[row * 64 + ((blk ^ (row & 7)) << 3)];
      }
      #pragma unroll
      for (int ni = 0; ni < 4; ++ni) {
        const int row = wc * 64 + ni * 16 + lr;
        bF[ni] = *(const bf16x8*)&smB[row * 64 + ((blk ^ (row & 7)) << 3)];
      }
      #pragma unroll
      for (int mi = 0; mi < 4; ++mi)
        #pragma unroll
        for (int ni = 0; ni < 4; ++ni) {
          if (SWAP)
            acc[mi][ni] = __builtin_amdgcn_mfma_f32_16x16x32_bf16(
                bF[ni], aF[mi], acc[mi][ni], 0, 0, 0);   // reg axis = n
          else
            acc[mi][ni] = __builtin_amdgcn_mfma_f32_16x16x32_bf16(
                aF[mi], bF[ni], acc[mi][ni], 0, 0, 0);   // reg axis = m
        }
    }
    __syncthreads();
  }

  if (!SWAP) {
    // coalesced scalar epilogue: m = reg axis, n = lane axis
    #pragma unroll
    for (int mi = 0; mi < 4; ++mi)
      #pragma unroll
      for (int ni = 0; ni < 4; ++ni)
        #pragma unroll
        for (int r = 0; r < 4; ++r) {
          const int grow = m0 + wr * 64 + mi * 16 + lg * 4 + r;
          const int gcol = n0 + wc * 64 + ni * 16 + lr;
          const size_t idx = (size_t)grow * LDC + gcol;
          if (MODE == 0) {
            outb[idx] = f2b(acc[mi][ni][r]);
          } else if (MODE == 1) {
            const float a = acc[mi][ni][r] + bias[gcol];
            const float cdf = 0.5f * (1.0f + erff(a * 0.70710678118654752f));
            outb[idx] = f2b(a * cdf);
          } else {
            outf[idx] = b2f(Qb[idx]) + acc[mi][ni][r] + bias[gcol];
          }
        }
  } else {
    // per-lane vector epilogue: n = reg axis (4 consecutive cols)
    #pragma unroll
    for (int mi = 0; mi < 4; ++mi) {
      const int m = m0 + wr * 64 + mi * 16 + lr;
      #pragma unroll
      for (int ni = 0; ni < 4; ++ni) {
        const int nb = n0 + wc * 64 + ni * 16 + lg * 4;
        const size_t idx = (size_t)m * LDC + nb;
        if (MODE == 0) {
          ushort4 v;
          v.x = f2b(acc[mi][ni][0]); v.y = f2b(acc[mi][ni][1]);
          v.z = f2b(acc[mi][ni][2]); v.w = f2b(acc[mi][ni][3]);
          *(ushort4*)&outb[idx] = v;
        } else if (MODE == 1) {
          const float4 b4 = *(const float4*)&bias[nb];
          ushort4 v;
          #pragma unroll
          for (int r = 0; r < 4; ++r) {
            const float a = acc[mi][ni][r] + ((const float*)&b4)[r];
            const float cdf = 0.5f * (1.0f + erff(a * 0.70710678118654752f));
            ((u16*)&v)[r] = f2b(a * cdf);
          }
          *(ushort4*)&outb[idx] = v;
        } else {
          const float4 b4 = *(const float4*)&bias[nb];
          const ushort4 q4 = *(const ushort4*)&Qb[idx];
          float4 o;
          o.x = b2f(q4.x) + acc[mi][ni][0] + b4.x;
          o.y = b2f(q4.y) + acc[mi][ni][1] + b4.y;
          o.z = b2f(q4.z) + acc[mi][ni][2] + b4.z;
          o.w = b2f(q4.w) + acc[mi][ni][3] + b4.w;
          *(float4*)&outf[idx] = o;
        }
      }
    }
  }
}

// ---------------------------------------------------------------------------
extern "C" void kernel_launch(void* const* d_in, const int* in_sizes, int n_in,
                              void* d_out, int out_size, void* d_ws, size_t ws_size,
                              hipStream_t stream)
{
  const float* in_seq = (const float*)d_in[0];
  const float* t_q = (const float*)d_in[3];
  const float* W1  = (const float*)d_in[4];
  const float* b1  = (const float*)d_in[5];
  const float* W2  = (const float*)d_in[6];
  const float* b2  = (const float*)d_in[7];
  float* out = (float*)d_out;

  char* p = (char*)d_ws;
  u16* Xb  = (u16*)p;  p += (size_t)MROWS * DD * sizeof(u16);   // 64 MiB
  u16* Qb  = (u16*)p;  p += (size_t)MROWS * HH * sizeof(u16);   // 64 MiB
  u16* Wqb = (u16*)p;  p += (size_t)HH * DD * sizeof(u16);      // 2 MiB
  u16* W1b = (u16*)p;  p += (size_t)H4 * HH * sizeof(u16);
  u16* W2b = (u16*)p;  p += (size_t)HH * H4 * sizeof(u16);
  u16* h2  = Xb;                                                // alias

  k_cvt<<<17152, 256, 0, stream>>>(in_seq, t_q, W1, W2, Xb, Wqb, W1b, W2b);

  // Q = X @ t_q^T   (unswapped coalesced epilogue, XCD-aware 1D decode)
  k_gemm<0, 0, 1, DD, DD, DD, HH><<<2048, 256, 0, stream>>>(
      Xb, Wqb, nullptr, nullptr, Qb, nullptr);
  // h2 = gelu(Q @ W1^T + b1)   (swapped vector epilogue)
  k_gemm<1, 1, 0, HH, HH, HH, H4><<<dim3(256, 2), 256, 0, stream>>>(
      Qb, W1b, b1, nullptr, h2, nullptr);
  // out = Q + h2 @ W2^T + b2   (swapped vector epilogue)
  k_gemm<2, 1, 0, H4, H4, H4, HH><<<dim3(256, 8), 256, 0, stream>>>(
      h2, W2b, b2, Qb, nullptr, out);
}

// Round 17
// 209.796 us; speedup vs baseline: 1.0272x; 1.0272x over previous
//
#include <hip/hip_runtime.h>

// ---------------------------------------------------------------------------
// TTLinear on MI355X — round 16: revert R15's XCD swizzle (measured 110->265MB
// FETCH: the 2D grid's implicit x%8 mapping already pinned each A-panel to one
// XCD; the 1D remap duplicated panels across all 8 L2s). Back to R14 (203.3us
// proven) + one delta: l2 hoists its 16 residual ushort4 loads to kernel
// entry so the 64MB Qb stream's latency hides under the K-loop instead of
// serializing into the epilogue.
//   k_cvt : X, t_q, W1, W2 -> bf16 (memory floor)
//   k_q   : Q = X @ t_q^T          (m97 128x128, unswapped coalesced epilogue)
//   k_l1  : h2 = gelu(Q@W1^T+b1)   (swapped vector epilogue)
//   k_l2  : out = Q + h2@W2^T + b2 (swapped, early residual prefetch)
// ---------------------------------------------------------------------------

#define DD      1024
#define HH      1024
#define H4      256
#define MROWS   32768          // T*N = 128*256

typedef unsigned short u16;
typedef __bf16 bf16x8 __attribute__((ext_vector_type(8)));
typedef float  f32x4  __attribute__((ext_vector_type(4)));

__device__ __forceinline__ u16 f2b(float x) {            // fp32 -> bf16 (RNE)
  unsigned u = __builtin_bit_cast(unsigned, x);
  unsigned r = (u + 0x7fffu + ((u >> 16) & 1u)) >> 16;
  return (u16)r;
}
__device__ __forceinline__ float b2f(u16 x) {
  return __builtin_bit_cast(float, ((unsigned)x) << 16);
}

__device__ __forceinline__ void gload16(const u16* g, u16* l) {
  __builtin_amdgcn_global_load_lds(
      (const __attribute__((address_space(1))) unsigned int*)g,
      (__attribute__((address_space(3))) unsigned int*)l, 16, 0, 0);
}

// ---------------------------------------------------------------------------
// fp32 -> bf16 bulk convert, 8 elems/thread; all four tensors in one launch.
// ---------------------------------------------------------------------------
__device__ __forceinline__ void cvt8_at(u16* dst, const float* src, size_t i) {
  const float4* s = (const float4*)(src + i);
  const float4 f0 = s[0], f1 = s[1];
  uint4 pk;
  pk.x = (unsigned)f2b(f0.x) | ((unsigned)f2b(f0.y) << 16);
  pk.y = (unsigned)f2b(f0.z) | ((unsigned)f2b(f0.w) << 16);
  pk.z = (unsigned)f2b(f1.x) | ((unsigned)f2b(f1.y) << 16);
  pk.w = (unsigned)f2b(f1.z) | ((unsigned)f2b(f1.w) << 16);
  *(uint4*)(dst + i) = pk;
}

__global__ __launch_bounds__(256) void k_cvt(
    const float* __restrict__ X, const float* __restrict__ tq,
    const float* __restrict__ W1, const float* __restrict__ W2,
    u16* __restrict__ Xb, u16* __restrict__ tqb,
    u16* __restrict__ W1b, u16* __restrict__ W2b) {
  const int b = blockIdx.x;
  if (b < 16384)      cvt8_at(Xb,  X,  ((size_t)b * 256 + threadIdx.x) * 8);
  else if (b < 16896) cvt8_at(tqb, tq, ((size_t)(b - 16384) * 256 + threadIdx.x) * 8);
  else if (b < 17024) cvt8_at(W1b, W1, ((size_t)(b - 16896) * 256 + threadIdx.x) * 8);
  else                cvt8_at(W2b, W2, ((size_t)(b - 17024) * 256 + threadIdx.x) * 8);
}

// ---------------------------------------------------------------------------
// m97 128x128 bf16 MFMA GEMM.  C(m,n) = sum_k A[m][k] * B[n][k]
// SWAP=0: mfma(aF,bF) -> reg axis = m, lane axis = n (coalesced scalar st).
// SWAP=1: mfma(bF,aF) -> reg axis = n (per-lane ushort4/float4 epilogue).
// MODE 0: bf16 store.  MODE 1: gelu -> bf16.  MODE 2: fp32 residual + bias
//         (residual ushort4 loads prefetched at kernel entry).
// ---------------------------------------------------------------------------
template<int MODE, int SWAP, int LDA, int LDB, int K, int LDC>
__global__ __launch_bounds__(256) void k_gemm(
    const u16* __restrict__ A, const u16* __restrict__ B,
    const float* __restrict__ bias, const u16* __restrict__ Qb,
    u16* __restrict__ outb, float* __restrict__ outf)
{
  __shared__ u16 smA[128 * 64];
  __shared__ u16 smB[128 * 64];
  const int tid  = threadIdx.x;
  const int m0   = blockIdx.x * 128, n0 = blockIdx.y * 128;
  const int lane = tid & 63, w = tid >> 6;
  const int wr = w >> 1, wc = w & 1;
  const int lr = lane & 15, lg = lane >> 4;

  // MODE 2: issue the 16 residual loads NOW — latency hides under the K-loop.
  ushort4 q4p[4][4];
  if (MODE == 2 && SWAP) {
    #pragma unroll
    for (int mi = 0; mi < 4; ++mi) {
      const int m = m0 + wr * 64 + mi * 16 + lr;
      #pragma unroll
      for (int ni = 0; ni < 4; ++ni) {
        const int nb = n0 + wc * 64 + ni * 16 + lg * 4;
        q4p[mi][ni] = *(const ushort4*)&Qb[(size_t)m * LDC + nb];
      }
    }
  }

  const int r0 = w * 8 + (lane >> 3);
  const int cb = (lane & 7) ^ (r0 & 7);
  const u16* ga = A + (size_t)(m0 + r0) * LDA + cb * 8;
  const u16* gb = B + (size_t)(n0 + r0) * LDB + cb * 8;
  u16* lA = smA + w * 512;
  u16* lB = smB + w * 512;

  f32x4 acc[4][4];
  #pragma unroll
  for (int i = 0; i < 4; ++i)
    #pragma unroll
    for (int j = 0; j < 4; ++j) { f32x4 z = {0.f, 0.f, 0.f, 0.f}; acc[i][j] = z; }

  for (int k0 = 0; k0 < K; k0 += 64) {
    #pragma unroll
    for (int j = 0; j < 4; ++j) {
      gload16(ga + (size_t)j * 32 * LDA + k0, lA + j * 2048);
      gload16(gb + (size_t)j * 32 * LDB + k0, lB + j * 2048);
    }
    __syncthreads();
    #pragma unroll
    for (int kc = 0; kc < 2; ++kc) {
      const int blk = kc * 4 + lg;
      bf16x8 aF[4], bF[4];
      #pragma unroll
      for (int mi = 0; mi < 4; ++mi) {
        const int row = wr * 64 + mi * 16 + lr;
        aF[mi] = *(const bf16x8*)&smA[row * 64 + ((blk ^ (row & 7)) << 3)];
      }
      #pragma unroll
      for (int ni = 0; ni < 4; ++ni) {
        const int row = wc * 64 + ni * 16 + lr;
        bF[ni] = *(const bf16x8*)&smB[row * 64 + ((blk ^ (row & 7)) << 3)];
      }
      #pragma unroll
      for (int mi = 0; mi < 4; ++mi)
        #pragma unroll
        for (int ni = 0; ni < 4; ++ni) {
          if (SWAP)
            acc[mi][ni] = __builtin_amdgcn_mfma_f32_16x16x32_bf16(
                bF[ni], aF[mi], acc[mi][ni], 0, 0, 0);   // reg axis = n
          else
            acc[mi][ni] = __builtin_amdgcn_mfma_f32_16x16x32_bf16(
                aF[mi], bF[ni], acc[mi][ni], 0, 0, 0);   // reg axis = m
        }
    }
    __syncthreads();
  }

  if (!SWAP) {
    // coalesced scalar epilogue: m = reg axis, n = lane axis
    #pragma unroll
    for (int mi = 0; mi < 4; ++mi)
      #pragma unroll
      for (int ni = 0; ni < 4; ++ni)
        #pragma unroll
        for (int r = 0; r < 4; ++r) {
          const int grow = m0 + wr * 64 + mi * 16 + lg * 4 + r;
          const int gcol = n0 + wc * 64 + ni * 16 + lr;
          const size_t idx = (size_t)grow * LDC + gcol;
          if (MODE == 0) {
            outb[idx] = f2b(acc[mi][ni][r]);
          } else if (MODE == 1) {
            const float a = acc[mi][ni][r] + bias[gcol];
            const float cdf = 0.5f * (1.0f + erff(a * 0.70710678118654752f));
            outb[idx] = f2b(a * cdf);
          } else {
            outf[idx] = b2f(Qb[idx]) + acc[mi][ni][r] + bias[gcol];
          }
        }
  } else {
    // per-lane vector epilogue: n = reg axis (4 consecutive cols)
    #pragma unroll
    for (int mi = 0; mi < 4; ++mi) {
      const int m = m0 + wr * 64 + mi * 16 + lr;
      #pragma unroll
      for (int ni = 0; ni < 4; ++ni) {
        const int nb = n0 + wc * 64 + ni * 16 + lg * 4;
        const size_t idx = (size_t)m * LDC + nb;
        if (MODE == 0) {
          ushort4 v;
          v.x = f2b(acc[mi][ni][0]); v.y = f2b(acc[mi][ni][1]);
          v.z = f2b(acc[mi][ni][2]); v.w = f2b(acc[mi][ni][3]);
          *(ushort4*)&outb[idx] = v;
        } else if (MODE == 1) {
          const float4 b4 = *(const float4*)&bias[nb];
          ushort4 v;
          #pragma unroll
          for (int r = 0; r < 4; ++r) {
            const float a = acc[mi][ni][r] + ((const float*)&b4)[r];
            const float cdf = 0.5f * (1.0f + erff(a * 0.70710678118654752f));
            ((u16*)&v)[r] = f2b(a * cdf);
          }
          *(ushort4*)&outb[idx] = v;
        } else {
          const float4 b4 = *(const float4*)&bias[nb];
          const ushort4 q4 = q4p[mi][ni];
          float4 o;
          o.x = b2f(q4.x) + acc[mi][ni][0] + b4.x;
          o.y = b2f(q4.y) + acc[mi][ni][1] + b4.y;
          o.z = b2f(q4.z) + acc[mi][ni][2] + b4.z;
          o.w = b2f(q4.w) + acc[mi][ni][3] + b4.w;
          *(float4*)&outf[idx] = o;
        }
      }
    }
  }
}

// ---------------------------------------------------------------------------
extern "C" void kernel_launch(void* const* d_in, const int* in_sizes, int n_in,
                              void* d_out, int out_size, void* d_ws, size_t ws_size,
                              hipStream_t stream)
{
  const float* in_seq = (const float*)d_in[0];
  const float* t_q = (const float*)d_in[3];
  const float* W1  = (const float*)d_in[4];
  const float* b1  = (const float*)d_in[5];
  const float* W2  = (const float*)d_in[6];
  const float* b2  = (const float*)d_in[7];
  float* out = (float*)d_out;

  char* p = (char*)d_ws;
  u16* Xb  = (u16*)p;  p += (size_t)MROWS * DD * sizeof(u16);   // 64 MiB
  u16* Qb  = (u16*)p;  p += (size_t)MROWS * HH * sizeof(u16);   // 64 MiB
  u16* Wqb = (u16*)p;  p += (size_t)HH * DD * sizeof(u16);      // 2 MiB
  u16* W1b = (u16*)p;  p += (size_t)H4 * HH * sizeof(u16);
  u16* W2b = (u16*)p;  p += (size_t)HH * H4 * sizeof(u16);
  u16* h2  = Xb;                                                // alias

  k_cvt<<<17152, 256, 0, stream>>>(in_seq, t_q, W1, W2, Xb, Wqb, W1b, W2b);

  // Q = X @ t_q^T   (unswapped coalesced epilogue, 2D grid: A-panel->1 XCD)
  k_gemm<0, 0, DD, DD, DD, HH><<<dim3(256, 8), 256, 0, stream>>>(
      Xb, Wqb, nullptr, nullptr, Qb, nullptr);
  // h2 = gelu(Q @ W1^T + b1)
  k_gemm<1, 1, HH, HH, HH, H4><<<dim3(256, 2), 256, 0, stream>>>(
      Qb, W1b, b1, nullptr, h2, nullptr);
  // out = Q + h2 @ W2^T + b2   (early residual prefetch)
  k_gemm<2, 1, H4, H4, H4, HH><<<dim3(256, 8), 256, 0, stream>>>(
      h2, W2b, b2, Qb, nullptr, out);
}

// Round 18
// 203.452 us; speedup vs baseline: 1.0592x; 1.0312x over previous
//
#include <hip/hip_runtime.h>

// ---------------------------------------------------------------------------
// TTLinear on MI355X — round 17: restore the best measured configuration
// (R14, 203.3us). R17's residual-prefetch reverted (cost occupancy in l2,
// +6us). Final structure:
//   k_cvt : X, t_q, W1, W2 -> bf16 (single launch, ~32us = 197MB at BW floor)
//   k_q   : Q = X @ t_q^T          (m97 128x128, unswapped coalesced epilogue,
//                                   85.8us = m97-structure ceiling)
//   k_l1  : h2 = gelu(Q@W1^T+b1)   (swapped vector epilogue, ~25us)
//   k_l2  : out = Q + h2@W2^T + b2 (swapped vector epilogue, near 208MB floor)
// ---------------------------------------------------------------------------

#define DD      1024
#define HH      1024
#define H4      256
#define MROWS   32768          // T*N = 128*256

typedef unsigned short u16;
typedef __bf16 bf16x8 __attribute__((ext_vector_type(8)));
typedef float  f32x4  __attribute__((ext_vector_type(4)));

__device__ __forceinline__ u16 f2b(float x) {            // fp32 -> bf16 (RNE)
  unsigned u = __builtin_bit_cast(unsigned, x);
  unsigned r = (u + 0x7fffu + ((u >> 16) & 1u)) >> 16;
  return (u16)r;
}
__device__ __forceinline__ float b2f(u16 x) {
  return __builtin_bit_cast(float, ((unsigned)x) << 16);
}

__device__ __forceinline__ void gload16(const u16* g, u16* l) {
  __builtin_amdgcn_global_load_lds(
      (const __attribute__((address_space(1))) unsigned int*)g,
      (__attribute__((address_space(3))) unsigned int*)l, 16, 0, 0);
}

// ---------------------------------------------------------------------------
// fp32 -> bf16 bulk convert, 8 elems/thread; all four tensors in one launch.
// ---------------------------------------------------------------------------
__device__ __forceinline__ void cvt8_at(u16* dst, const float* src, size_t i) {
  const float4* s = (const float4*)(src + i);
  const float4 f0 = s[0], f1 = s[1];
  uint4 pk;
  pk.x = (unsigned)f2b(f0.x) | ((unsigned)f2b(f0.y) << 16);
  pk.y = (unsigned)f2b(f0.z) | ((unsigned)f2b(f0.w) << 16);
  pk.z = (unsigned)f2b(f1.x) | ((unsigned)f2b(f1.y) << 16);
  pk.w = (unsigned)f2b(f1.z) | ((unsigned)f2b(f1.w) << 16);
  *(uint4*)(dst + i) = pk;
}

__global__ __launch_bounds__(256) void k_cvt(
    const float* __restrict__ X, const float* __restrict__ tq,
    const float* __restrict__ W1, const float* __restrict__ W2,
    u16* __restrict__ Xb, u16* __restrict__ tqb,
    u16* __restrict__ W1b, u16* __restrict__ W2b) {
  const int b = blockIdx.x;
  if (b < 16384)      cvt8_at(Xb,  X,  ((size_t)b * 256 + threadIdx.x) * 8);
  else if (b < 16896) cvt8_at(tqb, tq, ((size_t)(b - 16384) * 256 + threadIdx.x) * 8);
  else if (b < 17024) cvt8_at(W1b, W1, ((size_t)(b - 16896) * 256 + threadIdx.x) * 8);
  else                cvt8_at(W2b, W2, ((size_t)(b - 17024) * 256 + threadIdx.x) * 8);
}

// ---------------------------------------------------------------------------
// m97 128x128 bf16 MFMA GEMM.  C(m,n) = sum_k A[m][k] * B[n][k]
// SWAP=0: mfma(aF,bF) -> reg axis = m, lane axis = n (coalesced scalar st).
// SWAP=1: mfma(bF,aF) -> reg axis = n (per-lane ushort4/float4 epilogue).
// MODE 0: bf16 store.  MODE 1: gelu -> bf16.  MODE 2: fp32 residual + bias.
// ---------------------------------------------------------------------------
template<int MODE, int SWAP, int LDA, int LDB, int K, int LDC>
__global__ __launch_bounds__(256) void k_gemm(
    const u16* __restrict__ A, const u16* __restrict__ B,
    const float* __restrict__ bias, const u16* __restrict__ Qb,
    u16* __restrict__ outb, float* __restrict__ outf)
{
  __shared__ u16 smA[128 * 64];
  __shared__ u16 smB[128 * 64];
  const int tid  = threadIdx.x;
  const int m0   = blockIdx.x * 128, n0 = blockIdx.y * 128;
  const int lane = tid & 63, w = tid >> 6;
  const int wr = w >> 1, wc = w & 1;
  const int lr = lane & 15, lg = lane >> 4;

  const int r0 = w * 8 + (lane >> 3);
  const int cb = (lane & 7) ^ (r0 & 7);
  const u16* ga = A + (size_t)(m0 + r0) * LDA + cb * 8;
  const u16* gb = B + (size_t)(n0 + r0) * LDB + cb * 8;
  u16* lA = smA + w * 512;
  u16* lB = smB + w * 512;

  f32x4 acc[4][4];
  #pragma unroll
  for (int i = 0; i < 4; ++i)
    #pragma unroll
    for (int j = 0; j < 4; ++j) { f32x4 z = {0.f, 0.f, 0.f, 0.f}; acc[i][j] = z; }

  for (int k0 = 0; k0 < K; k0 += 64) {
    #pragma unroll
    for (int j = 0; j < 4; ++j) {
      gload16(ga + (size_t)j * 32 * LDA + k0, lA + j * 2048);
      gload16(gb + (size_t)j * 32 * LDB + k0, lB + j * 2048);
    }
    __syncthreads();
    #pragma unroll
    for (int kc = 0; kc < 2; ++kc) {
      const int blk = kc * 4 + lg;
      bf16x8 aF[4], bF[4];
      #pragma unroll
      for (int mi = 0; mi < 4; ++mi) {
        const int row = wr * 64 + mi * 16 + lr;
        aF[mi] = *(const bf16x8*)&smA[row * 64 + ((blk ^ (row & 7)) << 3)];
      }
      #pragma unroll
      for (int ni = 0; ni < 4; ++ni) {
        const int row = wc * 64 + ni * 16 + lr;
        bF[ni] = *(const bf16x8*)&smB[row * 64 + ((blk ^ (row & 7)) << 3)];
      }
      #pragma unroll
      for (int mi = 0; mi < 4; ++mi)
        #pragma unroll
        for (int ni = 0; ni < 4; ++ni) {
          if (SWAP)
            acc[mi][ni] = __builtin_amdgcn_mfma_f32_16x16x32_bf16(
                bF[ni], aF[mi], acc[mi][ni], 0, 0, 0);   // reg axis = n
          else
            acc[mi][ni] = __builtin_amdgcn_mfma_f32_16x16x32_bf16(
                aF[mi], bF[ni], acc[mi][ni], 0, 0, 0);   // reg axis = m
        }
    }
    __syncthreads();
  }

  if (!SWAP) {
    // coalesced scalar epilogue: m = reg axis, n = lane axis
    #pragma unroll
    for (int mi = 0; mi < 4; ++mi)
      #pragma unroll
      for (int ni = 0; ni < 4; ++ni)
        #pragma unroll
        for (int r = 0; r < 4; ++r) {
          const int grow = m0 + wr * 64 + mi * 16 + lg * 4 + r;
          const int gcol = n0 + wc * 64 + ni * 16 + lr;
          const size_t idx = (size_t)grow * LDC + gcol;
          if (MODE == 0) {
            outb[idx] = f2b(acc[mi][ni][r]);
          } else if (MODE == 1) {
            const float a = acc[mi][ni][r] + bias[gcol];
            const float cdf = 0.5f * (1.0f + erff(a * 0.70710678118654752f));
            outb[idx] = f2b(a * cdf);
          } else {
            outf[idx] = b2f(Qb[idx]) + acc[mi][ni][r] + bias[gcol];
          }
        }
  } else {
    // per-lane vector epilogue: n = reg axis (4 consecutive cols)
    #pragma unroll
    for (int mi = 0; mi < 4; ++mi) {
      const int m = m0 + wr * 64 + mi * 16 + lr;
      #pragma unroll
      for (int ni = 0; ni < 4; ++ni) {
        const int nb = n0 + wc * 64 + ni * 16 + lg * 4;
        const size_t idx = (size_t)m * LDC + nb;
        if (MODE == 0) {
          ushort4 v;
          v.x = f2b(acc[mi][ni][0]); v.y = f2b(acc[mi][ni][1]);
          v.z = f2b(acc[mi][ni][2]); v.w = f2b(acc[mi][ni][3]);
          *(ushort4*)&outb[idx] = v;
        } else if (MODE == 1) {
          const float4 b4 = *(const float4*)&bias[nb];
          ushort4 v;
          #pragma unroll
          for (int r = 0; r < 4; ++r) {
            const float a = acc[mi][ni][r] + ((const float*)&b4)[r];
            const float cdf = 0.5f * (1.0f + erff(a * 0.70710678118654752f));
            ((u16*)&v)[r] = f2b(a * cdf);
          }
          *(ushort4*)&outb[idx] = v;
        } else {
          const float4 b4 = *(const float4*)&bias[nb];
          const ushort4 q4 = *(const ushort4*)&Qb[idx];
          float4 o;
          o.x = b2f(q4.x) + acc[mi][ni][0] + b4.x;
          o.y = b2f(q4.y) + acc[mi][ni][1] + b4.y;
          o.z = b2f(q4.z) + acc[mi][ni][2] + b4.z;
          o.w = b2f(q4.w) + acc[mi][ni][3] + b4.w;
          *(float4*)&outf[idx] = o;
        }
      }
    }
  }
}

// ---------------------------------------------------------------------------
extern "C" void kernel_launch(void* const* d_in, const int* in_sizes, int n_in,
                              void* d_out, int out_size, void* d_ws, size_t ws_size,
                              hipStream_t stream)
{
  const float* in_seq = (const float*)d_in[0];
  const float* t_q = (const float*)d_in[3];
  const float* W1  = (const float*)d_in[4];
  const float* b1  = (const float*)d_in[5];
  const float* W2  = (const float*)d_in[6];
  const float* b2  = (const float*)d_in[7];
  float* out = (float*)d_out;

  char* p = (char*)d_ws;
  u16* Xb  = (u16*)p;  p += (size_t)MROWS * DD * sizeof(u16);   // 64 MiB
  u16* Qb  = (u16*)p;  p += (size_t)MROWS * HH * sizeof(u16);   // 64 MiB
  u16* Wqb = (u16*)p;  p += (size_t)HH * DD * sizeof(u16);      // 2 MiB
  u16* W1b = (u16*)p;  p += (size_t)H4 * HH * sizeof(u16);
  u16* W2b = (u16*)p;  p += (size_t)HH * H4 * sizeof(u16);
  u16* h2  = Xb;                                                // alias

  k_cvt<<<17152, 256, 0, stream>>>(in_seq, t_q, W1, W2, Xb, Wqb, W1b, W2b);

  // Q = X @ t_q^T   (unswapped coalesced epilogue)
  k_gemm<0, 0, DD, DD, DD, HH><<<dim3(256, 8), 256, 0, stream>>>(
      Xb, Wqb, nullptr, nullptr, Qb, nullptr);
  // h2 = gelu(Q @ W1^T + b1)
  k_gemm<1, 1, HH, HH, HH, H4><<<dim3(256, 2), 256, 0, stream>>>(
      Qb, W1b, b1, nullptr, h2, nullptr);
  // out = Q + h2 @ W2^T + b2
  k_gemm<2, 1, H4, H4, H4, HH><<<dim3(256, 8), 256, 0, stream>>>(
      h2, W2b, b2, Qb, nullptr, out);
}